// Round 5
// baseline (252.518 us; speedup 1.0000x reference)
//
#include <hip/hip_runtime.h>
#include <math.h>

#define FDIM 256
#define NEG_SLOPE 0.2f

typedef _Float16 half4v __attribute__((ext_vector_type(4)));
typedef _Float16 half8v __attribute__((ext_vector_type(8)));
typedef float f32x4 __attribute__((ext_vector_type(4)));

// ---- phase1: histograms (pos graph by dst, query graph by u) + weight prep

__global__ void build_phase1(const int* __restrict__ pos_ei, const int* __restrict__ q_ei,
                             int* __restrict__ cnt, int* __restrict__ qcnt,
                             const float* __restrict__ W0, const float* __restrict__ W1,
                             const float* __restrict__ W2,
                             _Float16* __restrict__ Wt_hi, _Float16* __restrict__ Wt_lo,
                             int E_pos, int E_tot, int EQ, int nbE, int nbQ) {
    int b = blockIdx.x;
    int tid = threadIdx.x;
    if (b < nbE) {
        int e = b * 256 + tid;
        if (e < E_tot) {
            int d = (e < E_pos) ? pos_ei[E_pos + e] : (e - E_pos);
            atomicAdd(&cnt[d], 1);
        }
    } else if (b < nbE + nbQ) {
        int e = (b - nbE) * 256 + tid;
        if (e < EQ) atomicAdd(&qcnt[q_ei[e]], 1);
    } else {
        int idx = b - nbE - nbQ;          // 0..767
        int n = idx & 255, mat = idx >> 8;
        const float* W = (mat == 0) ? W0 : (mat == 1) ? W1 : W2;
        int k = tid;
        float v = W[k * FDIM + n];
        _Float16 hi = (_Float16)v;
        _Float16 lo = (_Float16)(v - (float)hi);
        size_t o = (size_t)mat * FDIM * FDIM + (size_t)n * FDIM + k;
        Wt_hi[o] = hi;
        Wt_lo[o] = lo;
    }
}

// ---- dual exclusive scan over two 10K count arrays -------------------------

__device__ void scan_body(const int* __restrict__ cnt, int* __restrict__ row_ptr,
                          int* __restrict__ fill, int N, int* sums) {
    const int CH = 10;
    int tid = threadIdx.x;
    int base = tid * CH;
    int vals[CH];
    int s = 0;
#pragma unroll
    for (int i = 0; i < CH; ++i) {
        int idx = base + i;
        int v = (idx < N) ? cnt[idx] : 0;
        vals[i] = s;
        s += v;
    }
    sums[tid] = s;
    __syncthreads();
    for (int off = 1; off < 1024; off <<= 1) {
        int v = (tid >= off) ? sums[tid - off] : 0;
        __syncthreads();
        sums[tid] += v;
        __syncthreads();
    }
    int toff = (tid == 0) ? 0 : sums[tid - 1];
#pragma unroll
    for (int i = 0; i < CH; ++i) {
        int idx = base + i;
        if (idx < N) {
            int rp = toff + vals[i];
            row_ptr[idx] = rp;
            fill[idx] = rp;
        }
    }
    if (tid == 0) row_ptr[N] = sums[1023];
}

__global__ __launch_bounds__(1024) void scan2(const int* __restrict__ cnt,
                                              int* __restrict__ row_ptr, int* __restrict__ fill,
                                              const int* __restrict__ qcnt,
                                              int* __restrict__ qrow_ptr, int* __restrict__ qfill,
                                              int N) {
    __shared__ int sums[1024];
    scan_body(cnt, row_ptr, fill, N, sums);
    __syncthreads();
    scan_body(qcnt, qrow_ptr, qfill, N, sums);
}

// ---- phase2: scatter both edge sets ---------------------------------------

__global__ void build_phase2(const int* __restrict__ pos_ei, const int* __restrict__ q_ei,
                             int* __restrict__ fill, int* __restrict__ srcs,
                             int* __restrict__ qfill, int* __restrict__ qdst,
                             int* __restrict__ qeid,
                             int E_pos, int E_tot, int EQ, int nbE) {
    int b = blockIdx.x;
    int tid = threadIdx.x;
    if (b < nbE) {
        int e = b * 256 + tid;
        if (e < E_tot) {
            int s, d;
            if (e < E_pos) { s = pos_ei[e]; d = pos_ei[E_pos + e]; }
            else           { s = e - E_pos; d = s; }
            int pos = atomicAdd(&fill[d], 1);
            srcs[pos] = s;
        }
    } else {
        int e = (b - nbE) * 256 + tid;
        if (e < EQ) {
            int u = q_ei[e];
            int pos = atomicAdd(&qfill[u], 1);
            qdst[pos] = q_ei[EQ + e];
            qeid[pos] = e;
        }
    }
}

// ------- split-f16 MFMA GEMM -----------------------------------------------
// MODE 0: A fp32 (inline split), C = split f16 (hi/lo) + bias   [Win]
// MODE 1: A pre-split f16 (hi/lo), C = f16, fused attn projections [W1,W2]

template <int MODE>
__global__ __launch_bounds__(256) void gemm_mfma(
        const float* __restrict__ A32,
        const _Float16* __restrict__ A_hi, const _Float16* __restrict__ A_lo,
        const _Float16* __restrict__ Bt_hi, const _Float16* __restrict__ Bt_lo,
        const float* __restrict__ bias,
        const float* __restrict__ a_src, const float* __restrict__ a_dst,
        float* __restrict__ al_s, float* __restrict__ al_d,
        _Float16* __restrict__ C_hi, _Float16* __restrict__ C_lo,
        int M) {
    __shared__ _Float16 As_hi[64][72];
    __shared__ _Float16 As_lo[64][72];
    __shared__ _Float16 Bs_hi[64][72];
    __shared__ _Float16 Bs_lo[64][72];
    int tid = threadIdx.x;
    int lane = tid & 63, w = tid >> 6;
    int wm = w >> 1, wn = w & 1;
    int quad = lane >> 4, l16 = lane & 15;
    int mBase = blockIdx.x * 64, nBase = blockIdx.y * 64;
    f32x4 acc[2][2] = {};

    for (int k0 = 0; k0 < FDIM; k0 += 64) {
        __syncthreads();
        if (MODE == 0) {
#pragma unroll
            for (int i = 0; i < 4; ++i) {
                int f = tid + i * 256;
                int m = f >> 4, kc = (f & 15) << 2;
                int row = mBase + m;
                float4 a = make_float4(0.f, 0.f, 0.f, 0.f);
                if (row < M) a = *(const float4*)(A32 + (size_t)row * FDIM + k0 + kc);
                _Float16 hx = (_Float16)a.x, hy = (_Float16)a.y;
                _Float16 hz = (_Float16)a.z, hw = (_Float16)a.w;
                half4v hi = {hx, hy, hz, hw};
                half4v lo = {(_Float16)(a.x - (float)hx), (_Float16)(a.y - (float)hy),
                             (_Float16)(a.z - (float)hz), (_Float16)(a.w - (float)hw)};
                *(half4v*)&As_hi[m][kc] = hi;
                *(half4v*)&As_lo[m][kc] = lo;
            }
        } else {
#pragma unroll
            for (int i = 0; i < 2; ++i) {
                int g = tid + i * 256;
                int m = g >> 3, gk = (g & 7) << 3;
                int row = mBase + m;
                half8v hi, lo;
                if (row < M) {
                    size_t off = (size_t)row * FDIM + k0 + gk;
                    hi = *(const half8v*)(A_hi + off);
                    lo = *(const half8v*)(A_lo + off);
                } else {
                    _Float16 z = (_Float16)0.f;
                    hi = (half8v){z, z, z, z, z, z, z, z};
                    lo = hi;
                }
                *(half8v*)&As_hi[m][gk] = hi;
                *(half8v*)&As_lo[m][gk] = lo;
            }
        }
#pragma unroll
        for (int i = 0; i < 2; ++i) {
            int g = tid + i * 256;
            int n = g >> 3, gk = (g & 7) << 3;
            size_t off = (size_t)(nBase + n) * FDIM + k0 + gk;
            *(half8v*)&Bs_hi[n][gk] = *(const half8v*)(Bt_hi + off);
            *(half8v*)&Bs_lo[n][gk] = *(const half8v*)(Bt_lo + off);
        }
        __syncthreads();
#pragma unroll
        for (int ks = 0; ks < 2; ++ks) {
            int kcol = ks * 32 + quad * 8;
            half8v aHi[2], aLo[2], bHi[2], bLo[2];
#pragma unroll
            for (int mt = 0; mt < 2; ++mt) {
                int r = wm * 32 + mt * 16 + l16;
                aHi[mt] = *(const half8v*)&As_hi[r][kcol];
                aLo[mt] = *(const half8v*)&As_lo[r][kcol];
            }
#pragma unroll
            for (int nt = 0; nt < 2; ++nt) {
                int c = wn * 32 + nt * 16 + l16;
                bHi[nt] = *(const half8v*)&Bs_hi[c][kcol];
                bLo[nt] = *(const half8v*)&Bs_lo[c][kcol];
            }
#pragma unroll
            for (int mt = 0; mt < 2; ++mt)
#pragma unroll
                for (int nt = 0; nt < 2; ++nt) {
                    acc[mt][nt] = __builtin_amdgcn_mfma_f32_16x16x32_f16(
                        aHi[mt], bHi[nt], acc[mt][nt], 0, 0, 0);
                    acc[mt][nt] = __builtin_amdgcn_mfma_f32_16x16x32_f16(
                        aHi[mt], bLo[nt], acc[mt][nt], 0, 0, 0);
                    acc[mt][nt] = __builtin_amdgcn_mfma_f32_16x16x32_f16(
                        aLo[mt], bHi[nt], acc[mt][nt], 0, 0, 0);
                }
        }
    }

    int col0 = nBase + wn * 32 + l16;
    int col1 = col0 + 16;
    if (MODE == 0) {
        float b0 = bias[col0], b1v = bias[col1];
#pragma unroll
        for (int mt = 0; mt < 2; ++mt) {
#pragma unroll
            for (int r = 0; r < 4; ++r) {
                int row = mBase + wm * 32 + mt * 16 + quad * 4 + r;
                if (row >= M) continue;
                float o0 = acc[mt][0][r] + b0;
                float o1 = acc[mt][1][r] + b1v;
                _Float16 h0 = (_Float16)o0, h1 = (_Float16)o1;
                size_t p0 = (size_t)row * FDIM + col0;
                size_t p1 = (size_t)row * FDIM + col1;
                C_hi[p0] = h0;              C_hi[p1] = h1;
                C_lo[p0] = (_Float16)(o0 - (float)h0);
                C_lo[p1] = (_Float16)(o1 - (float)h1);
            }
        }
    } else {
        float as0 = a_src[col0], as1 = a_src[col1];
        float ad0 = a_dst[col0], ad1 = a_dst[col1];
#pragma unroll
        for (int mt = 0; mt < 2; ++mt) {
#pragma unroll
            for (int r = 0; r < 4; ++r) {
                int row = mBase + wm * 32 + mt * 16 + quad * 4 + r;
                if (row < M) {
                    C_hi[(size_t)row * FDIM + col0] = (_Float16)acc[mt][0][r];
                    C_hi[(size_t)row * FDIM + col1] = (_Float16)acc[mt][1][r];
                }
                float ps = acc[mt][0][r] * as0 + acc[mt][1][r] * as1;
                float pd = acc[mt][0][r] * ad0 + acc[mt][1][r] * ad1;
#pragma unroll
                for (int off = 8; off; off >>= 1) {
                    ps += __shfl_xor(ps, off);
                    pd += __shfl_xor(pd, off);
                }
                if (l16 == 0 && row < M) {
                    atomicAdd(&al_s[row], ps);
                    atomicAdd(&al_d[row], pd);
                }
            }
        }
    }
}

// ------- fused edge-softmax + aggregation (wave per node, 8-deep gather) ---

__global__ __launch_bounds__(256) void softagg(
        const _Float16* __restrict__ t, const float* __restrict__ al_s,
        const float* __restrict__ al_d, const int* __restrict__ row_ptr,
        const int* __restrict__ srcs, const float* __restrict__ bias,
        _Float16* __restrict__ out_hi, _Float16* __restrict__ out_lo,
        float* __restrict__ out32, int N) {
    int wave = threadIdx.x >> 6, lane = threadIdx.x & 63;
    int node = blockIdx.x * 4 + wave;
    if (node >= N) return;
    int beg = row_ptr[node], end = row_ptr[node + 1];
    int deg = end - beg;
    float ad = al_d[node];
    const _Float16* tb = t + (size_t)lane * 4;
    float4 acc = make_float4(0.f, 0.f, 0.f, 0.f);
    float ssum = 0.f;

    if (deg <= 256) {
        float e[4];
        int sj[4];
#pragma unroll
        for (int c = 0; c < 4; ++c) {
            e[c] = -INFINITY;
            sj[c] = 0;
            int j = beg + c * 64 + lane;
            if (j < end) {
                int s = srcs[j];
                sj[c] = s;
                float ee = al_s[s] + ad;
                e[c] = (ee > 0.f) ? ee : NEG_SLOPE * ee;
            }
        }
        float m = fmaxf(fmaxf(e[0], e[1]), fmaxf(e[2], e[3]));
#pragma unroll
        for (int o = 32; o; o >>= 1) m = fmaxf(m, __shfl_xor(m, o));
        float ex[4];
#pragma unroll
        for (int c = 0; c < 4; ++c) {
            ex[c] = (e[c] == -INFINITY) ? 0.f : __expf(e[c] - m);
            ssum += ex[c];
        }
        // gather: 8 rows in flight; OOB lanes have ex=0, sj=0 (row 0, x0 = harmless)
#pragma unroll
        for (int c = 0; c < 4; ++c) {
            int jc = beg + c * 64;
            if (jc >= end) break;
            int cnt = min(64, end - jc);
            int rounds = (cnt + 7) >> 3;
            for (int g = 0; g < rounds; ++g) {
                int jj = g * 8;
                float av[8];
                int rv[8];
#pragma unroll
                for (int q = 0; q < 8; ++q) {
                    av[q] = __shfl(ex[c], jj + q);
                    rv[q] = __shfl(sj[c], jj + q);
                }
                half4v vv[8];
#pragma unroll
                for (int q = 0; q < 8; ++q)
                    vv[q] = *(const half4v*)(tb + (size_t)rv[q] * FDIM);
#pragma unroll
                for (int q = 0; q < 8; ++q) {
                    acc.x = fmaf(av[q], (float)vv[q].x, acc.x);
                    acc.y = fmaf(av[q], (float)vv[q].y, acc.y);
                    acc.z = fmaf(av[q], (float)vv[q].z, acc.z);
                    acc.w = fmaf(av[q], (float)vv[q].w, acc.w);
                }
            }
        }
    } else {
        float m = -INFINITY;
        for (int j = beg + lane; j < end; j += 64) {
            float ee = al_s[srcs[j]] + ad;
            ee = (ee > 0.f) ? ee : NEG_SLOPE * ee;
            m = fmaxf(m, ee);
        }
#pragma unroll
        for (int o = 32; o; o >>= 1) m = fmaxf(m, __shfl_xor(m, o));
        for (int jc = beg; jc < end; jc += 64) {
            int j = jc + lane;
            float ex = 0.f;
            int sr = 0;
            if (j < end) {
                sr = srcs[j];
                float ee = al_s[sr] + ad;
                ee = (ee > 0.f) ? ee : NEG_SLOPE * ee;
                ex = __expf(ee - m);
                ssum += ex;
            }
            int cnt = min(64, end - jc);
            int rounds = (cnt + 7) >> 3;
            for (int g = 0; g < rounds; ++g) {
                int jj = g * 8;
                float av[8];
                int rv[8];
#pragma unroll
                for (int q = 0; q < 8; ++q) {
                    av[q] = __shfl(ex, jj + q);
                    rv[q] = __shfl(sr, jj + q);
                }
                half4v vv[8];
#pragma unroll
                for (int q = 0; q < 8; ++q)
                    vv[q] = *(const half4v*)(tb + (size_t)rv[q] * FDIM);
#pragma unroll
                for (int q = 0; q < 8; ++q) {
                    acc.x = fmaf(av[q], (float)vv[q].x, acc.x);
                    acc.y = fmaf(av[q], (float)vv[q].y, acc.y);
                    acc.z = fmaf(av[q], (float)vv[q].z, acc.z);
                    acc.w = fmaf(av[q], (float)vv[q].w, acc.w);
                }
            }
        }
    }

#pragma unroll
    for (int o = 32; o; o >>= 1) ssum += __shfl_xor(ssum, o);
    float inv = 1.f / (ssum + 1e-16f);
    float4 bv = ((const float4*)bias)[lane];
    float ox = fmaf(acc.x, inv, bv.x);
    float oy = fmaf(acc.y, inv, bv.y);
    float oz = fmaf(acc.z, inv, bv.z);
    float ow = fmaf(acc.w, inv, bv.w);
    if (out32) {
        ((float4*)out32)[node * 64 + lane] = make_float4(ox, oy, oz, ow);
    } else {
        _Float16 hx = (_Float16)ox, hy = (_Float16)oy;
        _Float16 hz = (_Float16)oz, hw = (_Float16)ow;
        half4v hi = {hx, hy, hz, hw};
        half4v lo = {(_Float16)(ox - (float)hx), (_Float16)(oy - (float)hy),
                     (_Float16)(oz - (float)hz), (_Float16)(ow - (float)hw)};
        *(half4v*)(out_hi + (size_t)node * FDIM + lane * 4) = hi;
        *(half4v*)(out_lo + (size_t)node * FDIM + lane * 4) = lo;
    }
}

// -------- logits via u-CSR: wave per u, h[u] kept in registers -------------

__global__ __launch_bounds__(256) void edge_dot_csr(
        const float* __restrict__ h,
        const int* __restrict__ qrow_ptr, const int* __restrict__ qdst,
        const int* __restrict__ qeid, float* __restrict__ out, int N) {
    int w = threadIdx.x >> 6, lane = threadIdx.x & 63;
    int u = blockIdx.x * 4 + w;
    if (u >= N) return;
    int beg = qrow_ptr[u], end = qrow_ptr[u + 1];
    if (beg == end) return;
    float4 a = ((const float4*)(h + (size_t)u * FDIM))[lane];
    int j = beg;
    for (; j + 2 <= end; j += 2) {
        int v0 = qdst[j], v1 = qdst[j + 1];
        float4 b0 = ((const float4*)(h + (size_t)v0 * FDIM))[lane];
        float4 b1 = ((const float4*)(h + (size_t)v1 * FDIM))[lane];
        float s0 = a.x * b0.x + a.y * b0.y + a.z * b0.z + a.w * b0.w;
        float s1 = a.x * b1.x + a.y * b1.y + a.z * b1.z + a.w * b1.w;
#pragma unroll
        for (int o = 32; o; o >>= 1) {
            s0 += __shfl_down(s0, o);
            s1 += __shfl_down(s1, o);
        }
        if (lane == 0) {
            out[qeid[j]] = s0;
            out[qeid[j + 1]] = s1;
        }
    }
    if (j < end) {
        int v0 = qdst[j];
        float4 b0 = ((const float4*)(h + (size_t)v0 * FDIM))[lane];
        float s0 = a.x * b0.x + a.y * b0.y + a.z * b0.z + a.w * b0.w;
#pragma unroll
        for (int o = 32; o; o >>= 1) s0 += __shfl_down(s0, o);
        if (lane == 0) out[qeid[j]] = s0;
    }
}

// ---------------------------------------------------------------------------

extern "C" void kernel_launch(void* const* d_in, const int* in_sizes, int n_in,
                              void* d_out, int out_size, void* d_ws, size_t ws_size,
                              hipStream_t stream) {
    const float* x       = (const float*)d_in[0];
    const int*   pos_ei  = (const int*)d_in[1];
    const int*   q_ei    = (const int*)d_in[2];
    const float* Win_W   = (const float*)d_in[3];
    const float* Win_b   = (const float*)d_in[4];
    const float* W1      = (const float*)d_in[5];
    const float* a1_src  = (const float*)d_in[6];
    const float* a1_dst  = (const float*)d_in[7];
    const float* b1      = (const float*)d_in[8];
    const float* W2      = (const float*)d_in[9];
    const float* a2_src  = (const float*)d_in[10];
    const float* a2_dst  = (const float*)d_in[11];
    const float* b2      = (const float*)d_in[12];
    float* logits = (float*)d_out;

    const int N = in_sizes[0] / FDIM;   // 10000
    const int E_pos = in_sizes[1] / 2;  // 320000
    const int EQ = in_sizes[2] / 2;     // 100000
    const int E_tot = E_pos + N;        // 330000
    const size_t WMAT = (size_t)FDIM * FDIM;
    const size_t NF = (size_t)N * FDIM;

    // workspace carve-up
    _Float16* Wt_hi = (_Float16*)d_ws;          // 3*WMAT
    _Float16* Wt_lo = Wt_hi + 3 * WMAT;         // 3*WMAT
    _Float16* h0_hi = Wt_lo + 3 * WMAT;         // NF (also o2_hi)
    _Float16* h0_lo = h0_hi + NF;               // NF (also o2_lo)
    _Float16* t_h   = h0_lo + NF;               // NF
    float* h32   = (float*)(t_h + NF);          // NF fp32
    float* al_s1 = h32 + NF;                    // N -- zero region start
    float* al_d1 = al_s1 + N;                   // N
    float* al_s2 = al_d1 + N;                   // N
    float* al_d2 = al_s2 + N;                   // N
    int* cnt     = (int*)(al_d2 + N);           // N
    int* qcnt    = cnt + N;                     // N -- zero region end
    int* row_ptr = qcnt + N;                    // N+1
    int* fill    = row_ptr + (N + 1);           // N
    int* srcs    = fill + N;                    // E_tot
    int* qrow_ptr= srcs + E_tot;                // N+1
    int* qfill   = qrow_ptr + (N + 1);          // N
    int* qdst    = qfill + N;                   // EQ
    int* qeid    = qdst + EQ;                   // EQ

    hipMemsetAsync(al_s1, 0, (size_t)(4 * N) * sizeof(float) + (size_t)(2 * N) * sizeof(int), stream);

    int nbE = (E_tot + 255) / 256;
    int nbQ = (EQ + 255) / 256;

    // ---- CSR build (both graphs) + weight prep ----
    build_phase1<<<nbE + nbQ + 768, 256, 0, stream>>>(pos_ei, q_ei, cnt, qcnt,
                                                      Win_W, W1, W2, Wt_hi, Wt_lo,
                                                      E_pos, E_tot, EQ, nbE, nbQ);
    scan2<<<1, 1024, 0, stream>>>(cnt, row_ptr, fill, qcnt, qrow_ptr, qfill, N);
    build_phase2<<<nbE + nbQ, 256, 0, stream>>>(pos_ei, q_ei, fill, srcs,
                                                qfill, qdst, qeid, E_pos, E_tot, EQ, nbE);

    dim3 ggrid((N + 63) / 64, FDIM / 64);
    int nblk4 = (N + 3) / 4;

    // ---- input weighting: h0(split) = x @ Win_W + Win_b ----
    gemm_mfma<0><<<ggrid, 256, 0, stream>>>(x, nullptr, nullptr, Wt_hi, Wt_lo, Win_b,
                                            nullptr, nullptr, nullptr, nullptr,
                                            h0_hi, h0_lo, N);

    // ---- GAT layer 1 ----
    gemm_mfma<1><<<ggrid, 256, 0, stream>>>(nullptr, h0_hi, h0_lo,
                                            Wt_hi + WMAT, Wt_lo + WMAT, nullptr,
                                            a1_src, a1_dst, al_s1, al_d1,
                                            t_h, nullptr, N);
    softagg<<<nblk4, 256, 0, stream>>>(t_h, al_s1, al_d1, row_ptr, srcs, b1,
                                       h0_hi, h0_lo, nullptr, N);  // o2 aliases h0

    // ---- GAT layer 2 ----
    gemm_mfma<1><<<ggrid, 256, 0, stream>>>(nullptr, h0_hi, h0_lo,
                                            Wt_hi + 2 * WMAT, Wt_lo + 2 * WMAT, nullptr,
                                            a2_src, a2_dst, al_s2, al_d2,
                                            t_h, nullptr, N);
    softagg<<<nblk4, 256, 0, stream>>>(t_h, al_s2, al_d2, row_ptr, srcs, b2,
                                       nullptr, nullptr, h32, N);

    // ---- logits ----
    edge_dot_csr<<<nblk4, 256, 0, stream>>>(h32, qrow_ptr, qdst, qeid, logits, N);
}

// Round 6
// 238.037 us; speedup vs baseline: 1.0608x; 1.0608x over previous
//
#include <hip/hip_runtime.h>
#include <math.h>

#define FDIM 256
#define NEG_SLOPE 0.2f

typedef _Float16 half4v __attribute__((ext_vector_type(4)));
typedef _Float16 half8v __attribute__((ext_vector_type(8)));
typedef float f32x4 __attribute__((ext_vector_type(4)));

// ---- phase1: pos-graph histogram by dst + weight split prep ---------------

__global__ void build_phase1(const int* __restrict__ pos_ei,
                             int* __restrict__ cnt,
                             const float* __restrict__ W0, const float* __restrict__ W1,
                             const float* __restrict__ W2,
                             _Float16* __restrict__ Wt_hi, _Float16* __restrict__ Wt_lo,
                             int E_pos, int E_tot, int nbE) {
    int b = blockIdx.x;
    int tid = threadIdx.x;
    if (b < nbE) {
        int e = b * 256 + tid;
        if (e < E_tot) {
            int d = (e < E_pos) ? pos_ei[E_pos + e] : (e - E_pos);
            atomicAdd(&cnt[d], 1);
        }
    } else {
        int idx = b - nbE;                // 0..767
        int n = idx & 255, mat = idx >> 8;
        const float* W = (mat == 0) ? W0 : (mat == 1) ? W1 : W2;
        int k = tid;
        float v = W[k * FDIM + n];
        _Float16 hi = (_Float16)v;
        _Float16 lo = (_Float16)(v - (float)hi);
        size_t o = (size_t)mat * FDIM * FDIM + (size_t)n * FDIM + k;
        Wt_hi[o] = hi;
        Wt_lo[o] = lo;
    }
}

// ---- exclusive scan over 10K counts ---------------------------------------

__global__ __launch_bounds__(1024) void scan10k(const int* __restrict__ cnt,
                                                int* __restrict__ row_ptr,
                                                int* __restrict__ fill, int N) {
    const int CH = 10;
    __shared__ int sums[1024];
    int tid = threadIdx.x;
    int base = tid * CH;
    int vals[CH];
    int s = 0;
#pragma unroll
    for (int i = 0; i < CH; ++i) {
        int idx = base + i;
        int v = (idx < N) ? cnt[idx] : 0;
        vals[i] = s;
        s += v;
    }
    sums[tid] = s;
    __syncthreads();
    for (int off = 1; off < 1024; off <<= 1) {
        int v = (tid >= off) ? sums[tid - off] : 0;
        __syncthreads();
        sums[tid] += v;
        __syncthreads();
    }
    int toff = (tid == 0) ? 0 : sums[tid - 1];
#pragma unroll
    for (int i = 0; i < CH; ++i) {
        int idx = base + i;
        if (idx < N) {
            int rp = toff + vals[i];
            row_ptr[idx] = rp;
            fill[idx] = rp;
        }
    }
    if (tid == 0) row_ptr[N] = sums[1023];
}

// ---- phase2: scatter pos edges into dst-sorted order ----------------------

__global__ void scatter_edges(const int* __restrict__ pos_ei, int* __restrict__ fill,
                              int* __restrict__ srcs, int E_pos, int E_tot) {
    int e = blockIdx.x * blockDim.x + threadIdx.x;
    if (e < E_tot) {
        int s, d;
        if (e < E_pos) { s = pos_ei[e]; d = pos_ei[E_pos + e]; }
        else           { s = e - E_pos; d = s; }
        int pos = atomicAdd(&fill[d], 1);
        srcs[pos] = s;
    }
}

// ------- split-f16 MFMA GEMM -----------------------------------------------
// MODE 0: A fp32 (inline split), C = split f16 (hi/lo) + bias   [Win]
// MODE 1: A pre-split f16 (hi/lo), C = f16, fused attn projections [W1,W2]

template <int MODE>
__global__ __launch_bounds__(256) void gemm_mfma(
        const float* __restrict__ A32,
        const _Float16* __restrict__ A_hi, const _Float16* __restrict__ A_lo,
        const _Float16* __restrict__ Bt_hi, const _Float16* __restrict__ Bt_lo,
        const float* __restrict__ bias,
        const float* __restrict__ a_src, const float* __restrict__ a_dst,
        float* __restrict__ al_s, float* __restrict__ al_d,
        _Float16* __restrict__ C_hi, _Float16* __restrict__ C_lo,
        int M) {
    __shared__ _Float16 As_hi[64][72];
    __shared__ _Float16 As_lo[64][72];
    __shared__ _Float16 Bs_hi[64][72];
    __shared__ _Float16 Bs_lo[64][72];
    int tid = threadIdx.x;
    int lane = tid & 63, w = tid >> 6;
    int wm = w >> 1, wn = w & 1;
    int quad = lane >> 4, l16 = lane & 15;
    int mBase = blockIdx.x * 64, nBase = blockIdx.y * 64;
    f32x4 acc[2][2] = {};

    for (int k0 = 0; k0 < FDIM; k0 += 64) {
        __syncthreads();
        if (MODE == 0) {
#pragma unroll
            for (int i = 0; i < 4; ++i) {
                int f = tid + i * 256;
                int m = f >> 4, kc = (f & 15) << 2;
                int row = mBase + m;
                float4 a = make_float4(0.f, 0.f, 0.f, 0.f);
                if (row < M) a = *(const float4*)(A32 + (size_t)row * FDIM + k0 + kc);
                _Float16 hx = (_Float16)a.x, hy = (_Float16)a.y;
                _Float16 hz = (_Float16)a.z, hw = (_Float16)a.w;
                half4v hi = {hx, hy, hz, hw};
                half4v lo = {(_Float16)(a.x - (float)hx), (_Float16)(a.y - (float)hy),
                             (_Float16)(a.z - (float)hz), (_Float16)(a.w - (float)hw)};
                *(half4v*)&As_hi[m][kc] = hi;
                *(half4v*)&As_lo[m][kc] = lo;
            }
        } else {
#pragma unroll
            for (int i = 0; i < 2; ++i) {
                int g = tid + i * 256;
                int m = g >> 3, gk = (g & 7) << 3;
                int row = mBase + m;
                half8v hi, lo;
                if (row < M) {
                    size_t off = (size_t)row * FDIM + k0 + gk;
                    hi = *(const half8v*)(A_hi + off);
                    lo = *(const half8v*)(A_lo + off);
                } else {
                    _Float16 z = (_Float16)0.f;
                    hi = (half8v){z, z, z, z, z, z, z, z};
                    lo = hi;
                }
                *(half8v*)&As_hi[m][gk] = hi;
                *(half8v*)&As_lo[m][gk] = lo;
            }
        }
#pragma unroll
        for (int i = 0; i < 2; ++i) {
            int g = tid + i * 256;
            int n = g >> 3, gk = (g & 7) << 3;
            size_t off = (size_t)(nBase + n) * FDIM + k0 + gk;
            *(half8v*)&Bs_hi[n][gk] = *(const half8v*)(Bt_hi + off);
            *(half8v*)&Bs_lo[n][gk] = *(const half8v*)(Bt_lo + off);
        }
        __syncthreads();
#pragma unroll
        for (int ks = 0; ks < 2; ++ks) {
            int kcol = ks * 32 + quad * 8;
            half8v aHi[2], aLo[2], bHi[2], bLo[2];
#pragma unroll
            for (int mt = 0; mt < 2; ++mt) {
                int r = wm * 32 + mt * 16 + l16;
                aHi[mt] = *(const half8v*)&As_hi[r][kcol];
                aLo[mt] = *(const half8v*)&As_lo[r][kcol];
            }
#pragma unroll
            for (int nt = 0; nt < 2; ++nt) {
                int c = wn * 32 + nt * 16 + l16;
                bHi[nt] = *(const half8v*)&Bs_hi[c][kcol];
                bLo[nt] = *(const half8v*)&Bs_lo[c][kcol];
            }
#pragma unroll
            for (int mt = 0; mt < 2; ++mt)
#pragma unroll
                for (int nt = 0; nt < 2; ++nt) {
                    acc[mt][nt] = __builtin_amdgcn_mfma_f32_16x16x32_f16(
                        aHi[mt], bHi[nt], acc[mt][nt], 0, 0, 0);
                    acc[mt][nt] = __builtin_amdgcn_mfma_f32_16x16x32_f16(
                        aHi[mt], bLo[nt], acc[mt][nt], 0, 0, 0);
                    acc[mt][nt] = __builtin_amdgcn_mfma_f32_16x16x32_f16(
                        aLo[mt], bHi[nt], acc[mt][nt], 0, 0, 0);
                }
        }
    }

    int col0 = nBase + wn * 32 + l16;
    int col1 = col0 + 16;
    if (MODE == 0) {
        float b0 = bias[col0], b1v = bias[col1];
#pragma unroll
        for (int mt = 0; mt < 2; ++mt) {
#pragma unroll
            for (int r = 0; r < 4; ++r) {
                int row = mBase + wm * 32 + mt * 16 + quad * 4 + r;
                if (row >= M) continue;
                float o0 = acc[mt][0][r] + b0;
                float o1 = acc[mt][1][r] + b1v;
                _Float16 h0 = (_Float16)o0, h1 = (_Float16)o1;
                size_t p0 = (size_t)row * FDIM + col0;
                size_t p1 = (size_t)row * FDIM + col1;
                C_hi[p0] = h0;              C_hi[p1] = h1;
                C_lo[p0] = (_Float16)(o0 - (float)h0);
                C_lo[p1] = (_Float16)(o1 - (float)h1);
            }
        }
    } else {
        float as0 = a_src[col0], as1 = a_src[col1];
        float ad0 = a_dst[col0], ad1 = a_dst[col1];
#pragma unroll
        for (int mt = 0; mt < 2; ++mt) {
#pragma unroll
            for (int r = 0; r < 4; ++r) {
                int row = mBase + wm * 32 + mt * 16 + quad * 4 + r;
                if (row < M) {
                    C_hi[(size_t)row * FDIM + col0] = (_Float16)acc[mt][0][r];
                    C_hi[(size_t)row * FDIM + col1] = (_Float16)acc[mt][1][r];
                }
                float ps = acc[mt][0][r] * as0 + acc[mt][1][r] * as1;
                float pd = acc[mt][0][r] * ad0 + acc[mt][1][r] * ad1;
#pragma unroll
                for (int off = 8; off; off >>= 1) {
                    ps += __shfl_xor(ps, off);
                    pd += __shfl_xor(pd, off);
                }
                if (l16 == 0 && row < M) {
                    atomicAdd(&al_s[row], ps);
                    atomicAdd(&al_d[row], pd);
                }
            }
        }
    }
}

// ------- fused edge-softmax + aggregation (wave per node, register-cached) -
// (round-4 verified form: 4-wide gather groups + serial remainder)

__global__ __launch_bounds__(256) void softagg(
        const _Float16* __restrict__ t, const float* __restrict__ al_s,
        const float* __restrict__ al_d, const int* __restrict__ row_ptr,
        const int* __restrict__ srcs, const float* __restrict__ bias,
        _Float16* __restrict__ out_hi, _Float16* __restrict__ out_lo,
        float* __restrict__ out32, int N) {
    int wave = threadIdx.x >> 6, lane = threadIdx.x & 63;
    int node = blockIdx.x * 4 + wave;
    if (node >= N) return;
    int beg = row_ptr[node], end = row_ptr[node + 1];
    int deg = end - beg;
    float ad = al_d[node];
    const _Float16* tb = t + (size_t)lane * 4;
    float4 acc = make_float4(0.f, 0.f, 0.f, 0.f);
    float ssum = 0.f;

    if (deg <= 256) {
        float e[4];
        int sj[4];
#pragma unroll
        for (int c = 0; c < 4; ++c) {
            e[c] = -INFINITY;
            sj[c] = 0;
            int j = beg + c * 64 + lane;
            if (j < end) {
                int s = srcs[j];
                sj[c] = s;
                float ee = al_s[s] + ad;
                e[c] = (ee > 0.f) ? ee : NEG_SLOPE * ee;
            }
        }
        float m = fmaxf(fmaxf(e[0], e[1]), fmaxf(e[2], e[3]));
#pragma unroll
        for (int o = 32; o; o >>= 1) m = fmaxf(m, __shfl_xor(m, o));
        float ex[4];
#pragma unroll
        for (int c = 0; c < 4; ++c) {
            ex[c] = (e[c] == -INFINITY) ? 0.f : __expf(e[c] - m);
            ssum += ex[c];
        }
#pragma unroll
        for (int c = 0; c < 4; ++c) {
            int jc = beg + c * 64;
            if (jc >= end) break;
            int cnt = min(64, end - jc);
            int jj = 0;
            for (; jj + 4 <= cnt; jj += 4) {
                float a0 = __shfl(ex[c], jj + 0), a1 = __shfl(ex[c], jj + 1);
                float a2 = __shfl(ex[c], jj + 2), a3 = __shfl(ex[c], jj + 3);
                int r0 = __shfl(sj[c], jj + 0), r1 = __shfl(sj[c], jj + 1);
                int r2 = __shfl(sj[c], jj + 2), r3 = __shfl(sj[c], jj + 3);
                half4v v0 = *(const half4v*)(tb + (size_t)r0 * FDIM);
                half4v v1 = *(const half4v*)(tb + (size_t)r1 * FDIM);
                half4v v2 = *(const half4v*)(tb + (size_t)r2 * FDIM);
                half4v v3 = *(const half4v*)(tb + (size_t)r3 * FDIM);
                acc.x = fmaf(a0, (float)v0.x, acc.x); acc.y = fmaf(a0, (float)v0.y, acc.y);
                acc.z = fmaf(a0, (float)v0.z, acc.z); acc.w = fmaf(a0, (float)v0.w, acc.w);
                acc.x = fmaf(a1, (float)v1.x, acc.x); acc.y = fmaf(a1, (float)v1.y, acc.y);
                acc.z = fmaf(a1, (float)v1.z, acc.z); acc.w = fmaf(a1, (float)v1.w, acc.w);
                acc.x = fmaf(a2, (float)v2.x, acc.x); acc.y = fmaf(a2, (float)v2.y, acc.y);
                acc.z = fmaf(a2, (float)v2.z, acc.z); acc.w = fmaf(a2, (float)v2.w, acc.w);
                acc.x = fmaf(a3, (float)v3.x, acc.x); acc.y = fmaf(a3, (float)v3.y, acc.y);
                acc.z = fmaf(a3, (float)v3.z, acc.z); acc.w = fmaf(a3, (float)v3.w, acc.w);
            }
            for (; jj < cnt; ++jj) {
                float a = __shfl(ex[c], jj);
                int r = __shfl(sj[c], jj);
                half4v v = *(const half4v*)(tb + (size_t)r * FDIM);
                acc.x = fmaf(a, (float)v.x, acc.x); acc.y = fmaf(a, (float)v.y, acc.y);
                acc.z = fmaf(a, (float)v.z, acc.z); acc.w = fmaf(a, (float)v.w, acc.w);
            }
        }
    } else {
        float m = -INFINITY;
        for (int j = beg + lane; j < end; j += 64) {
            float ee = al_s[srcs[j]] + ad;
            ee = (ee > 0.f) ? ee : NEG_SLOPE * ee;
            m = fmaxf(m, ee);
        }
#pragma unroll
        for (int o = 32; o; o >>= 1) m = fmaxf(m, __shfl_xor(m, o));
        for (int jc = beg; jc < end; jc += 64) {
            int j = jc + lane;
            float ex = 0.f;
            int sr = 0;
            if (j < end) {
                sr = srcs[j];
                float ee = al_s[sr] + ad;
                ee = (ee > 0.f) ? ee : NEG_SLOPE * ee;
                ex = __expf(ee - m);
                ssum += ex;
            }
            int cnt = min(64, end - jc);
            for (int jj = 0; jj < cnt; ++jj) {
                float a = __shfl(ex, jj);
                int r = __shfl(sr, jj);
                half4v v = *(const half4v*)(tb + (size_t)r * FDIM);
                acc.x = fmaf(a, (float)v.x, acc.x); acc.y = fmaf(a, (float)v.y, acc.y);
                acc.z = fmaf(a, (float)v.z, acc.z); acc.w = fmaf(a, (float)v.w, acc.w);
            }
        }
    }

#pragma unroll
    for (int o = 32; o; o >>= 1) ssum += __shfl_xor(ssum, o);
    float inv = 1.f / (ssum + 1e-16f);
    float4 bv = ((const float4*)bias)[lane];
    float ox = fmaf(acc.x, inv, bv.x);
    float oy = fmaf(acc.y, inv, bv.y);
    float oz = fmaf(acc.z, inv, bv.z);
    float ow = fmaf(acc.w, inv, bv.w);
    if (out32) {
        ((float4*)out32)[node * 64 + lane] = make_float4(ox, oy, oz, ow);
    } else {
        _Float16 hx = (_Float16)ox, hy = (_Float16)oy;
        _Float16 hz = (_Float16)oz, hw = (_Float16)ow;
        half4v hi = {hx, hy, hz, hw};
        half4v lo = {(_Float16)(ox - (float)hx), (_Float16)(oy - (float)hy),
                     (_Float16)(oz - (float)hz), (_Float16)(ow - (float)hw)};
        *(half4v*)(out_hi + (size_t)node * FDIM + lane * 4) = hi;
        *(half4v*)(out_lo + (size_t)node * FDIM + lane * 4) = lo;
    }
}

// -------- logits: wave per edge (round-4 verified form) --------------------

__global__ __launch_bounds__(256) void edge_dot(const float* __restrict__ h,
                                                const int* __restrict__ ei,
                                                float* __restrict__ out, int EQ) {
    int w = threadIdx.x >> 6, lane = threadIdx.x & 63;
    int e = blockIdx.x * 4 + w;
    if (e >= EQ) return;
    int u = ei[e], v = ei[EQ + e];
    const float4* hu = (const float4*)(h + (size_t)u * FDIM);
    const float4* hv = (const float4*)(h + (size_t)v * FDIM);
    float4 a = hu[lane], b = hv[lane];
    float s = a.x * b.x + a.y * b.y + a.z * b.z + a.w * b.w;
#pragma unroll
    for (int o = 32; o; o >>= 1) s += __shfl_down(s, o);
    if (lane == 0) out[e] = s;
}

// ---------------------------------------------------------------------------

extern "C" void kernel_launch(void* const* d_in, const int* in_sizes, int n_in,
                              void* d_out, int out_size, void* d_ws, size_t ws_size,
                              hipStream_t stream) {
    const float* x       = (const float*)d_in[0];
    const int*   pos_ei  = (const int*)d_in[1];
    const int*   q_ei    = (const int*)d_in[2];
    const float* Win_W   = (const float*)d_in[3];
    const float* Win_b   = (const float*)d_in[4];
    const float* W1      = (const float*)d_in[5];
    const float* a1_src  = (const float*)d_in[6];
    const float* a1_dst  = (const float*)d_in[7];
    const float* b1      = (const float*)d_in[8];
    const float* W2      = (const float*)d_in[9];
    const float* a2_src  = (const float*)d_in[10];
    const float* a2_dst  = (const float*)d_in[11];
    const float* b2      = (const float*)d_in[12];
    float* logits = (float*)d_out;

    const int N = in_sizes[0] / FDIM;   // 10000
    const int E_pos = in_sizes[1] / 2;  // 320000
    const int EQ = in_sizes[2] / 2;     // 100000
    const int E_tot = E_pos + N;        // 330000
    const size_t WMAT = (size_t)FDIM * FDIM;
    const size_t NF = (size_t)N * FDIM;

    // workspace carve-up
    _Float16* Wt_hi = (_Float16*)d_ws;          // 3*WMAT
    _Float16* Wt_lo = Wt_hi + 3 * WMAT;         // 3*WMAT
    _Float16* h0_hi = Wt_lo + 3 * WMAT;         // NF (also o2_hi)
    _Float16* h0_lo = h0_hi + NF;               // NF (also o2_lo)
    _Float16* t_h   = h0_lo + NF;               // NF
    float* h32   = (float*)(t_h + NF);          // NF fp32
    float* al_s1 = h32 + NF;                    // N -- zero region start
    float* al_d1 = al_s1 + N;                   // N
    float* al_s2 = al_d1 + N;                   // N
    float* al_d2 = al_s2 + N;                   // N
    int* cnt     = (int*)(al_d2 + N);           // N -- zero region end
    int* row_ptr = cnt + N;                     // N+1
    int* fill    = row_ptr + (N + 1);           // N
    int* srcs    = fill + N;                    // E_tot

    hipMemsetAsync(al_s1, 0, (size_t)(4 * N) * sizeof(float) + (size_t)N * sizeof(int), stream);

    int nbE = (E_tot + 255) / 256;

    // ---- CSR build + weight prep ----
    build_phase1<<<nbE + 768, 256, 0, stream>>>(pos_ei, cnt, Win_W, W1, W2,
                                                Wt_hi, Wt_lo, E_pos, E_tot, nbE);
    scan10k<<<1, 1024, 0, stream>>>(cnt, row_ptr, fill, N);
    scatter_edges<<<nbE, 256, 0, stream>>>(pos_ei, fill, srcs, E_pos, E_tot);

    dim3 ggrid((N + 63) / 64, FDIM / 64);
    int nblk4 = (N + 3) / 4;

    // ---- input weighting: h0(split) = x @ Win_W + Win_b ----
    gemm_mfma<0><<<ggrid, 256, 0, stream>>>(x, nullptr, nullptr, Wt_hi, Wt_lo, Win_b,
                                            nullptr, nullptr, nullptr, nullptr,
                                            h0_hi, h0_lo, N);

    // ---- GAT layer 1 ----
    gemm_mfma<1><<<ggrid, 256, 0, stream>>>(nullptr, h0_hi, h0_lo,
                                            Wt_hi + WMAT, Wt_lo + WMAT, nullptr,
                                            a1_src, a1_dst, al_s1, al_d1,
                                            t_h, nullptr, N);
    softagg<<<nblk4, 256, 0, stream>>>(t_h, al_s1, al_d1, row_ptr, srcs, b1,
                                       h0_hi, h0_lo, nullptr, N);  // o2 aliases h0

    // ---- GAT layer 2 ----
    gemm_mfma<1><<<ggrid, 256, 0, stream>>>(nullptr, h0_hi, h0_lo,
                                            Wt_hi + 2 * WMAT, Wt_lo + 2 * WMAT, nullptr,
                                            a2_src, a2_dst, al_s2, al_d2,
                                            t_h, nullptr, N);
    softagg<<<nblk4, 256, 0, stream>>>(t_h, al_s2, al_d2, row_ptr, srcs, b2,
                                       nullptr, nullptr, h32, N);

    // ---- logits ----
    edge_dot<<<(EQ + 3) / 4, 256, 0, stream>>>(h32, q_ei, logits, EQ);
}